// Round 3
// baseline (153.547 us; speedup 1.0000x reference)
//
#include <hip/hip_runtime.h>

// DGCLoss: 1 - mean NDCG. N=384 rows, D=256 feats, M=383 off-diag cols.
//
// Round 3: grid-starve + launch-count fix. Fixed harness floor is ~40us
// (0xAA poison of the 268MB ws); controllable part is the 3 kernels below.
//   dgc_norm : wave-per-row normalize X -> XN; zero dcg/ticket.
//   dgc_sim  : block n, 768 thr (K split in half): S row + idcg[n].
//   dgc_body : block (grp,n): sigmoid sums -> dcg[n] atomics; last block
//              (device-scope ticket) reduces dcg/idcg -> out. No 4th launch.

#define NN 384
#define DD 256
#define MM 383
// exp(-d*1000) == exp2((s_i - s_j)) with s = ((cos+1)*0.5)*SCALE
#define HSCALE 721.3475204444817f   // 0.5 * 1000 * log2(e)

__global__ __launch_bounds__(256) void dgc_norm(const float* __restrict__ x,
                                                float* __restrict__ XN,
                                                float* __restrict__ dcg,
                                                unsigned* __restrict__ ticket) {
    const int t    = threadIdx.x;
    const int lane = t & 63;
    const int w    = t >> 6;
    const int r    = blockIdx.x * 4 + w;          // 96 blocks * 4 rows = 384

    float4 v = ((const float4*)(x + (size_t)r * DD))[lane];   // 64 lanes * 4 = 256
    float ss = v.x * v.x + v.y * v.y + v.z * v.z + v.w * v.w;
    #pragma unroll
    for (int off = 32; off > 0; off >>= 1) ss += __shfl_down(ss, off, 64);
    ss = __shfl(ss, 0, 64);
    const float invn = __builtin_amdgcn_rsqf(fmaxf(ss, 1e-16f));
    float4 o;
    o.x = v.x * invn; o.y = v.y * invn; o.z = v.z * invn; o.w = v.w * invn;
    ((float4*)(XN + (size_t)r * DD))[lane] = o;

    const int gi = blockIdx.x * 256 + t;
    if (gi < NN) dcg[gi] = 0.0f;
    if (gi == 0) *ticket = 0u;
}

__global__ __launch_bounds__(768) void dgc_sim(const float* __restrict__ XN,
                                               const int* __restrict__ gt,
                                               float* __restrict__ S,
                                               float* __restrict__ idcg) {
    __shared__ float xs[DD];       // normalized row n
    __shared__ float part[NN];     // K-half partial dots
    __shared__ float red[12];
    __shared__ int   hist[6];
    __shared__ int   cum[6];

    const int n    = blockIdx.x;
    const int t    = threadIdx.x;
    const int lane = t & 63;
    const int wave = t >> 6;

    if (t < DD / 4) ((float4*)xs)[t] = ((const float4*)(XN + (size_t)n * DD))[t];
    if (t < 6) hist[t] = 0;
    __syncthreads();

    // ---- S row: thread pair (j, j+384) splits K in half ----
    const int kh = (t >= NN) ? 1 : 0;
    const int j  = t - kh * NN;
    {
        const float4* xj = (const float4*)(XN + (size_t)j * DD) + kh * 32;
        const float4* xa = (const float4*)xs + kh * 32;
        float dot = 0.0f;
        #pragma unroll 8
        for (int k = 0; k < 32; ++k) {
            float4 a = xa[k], b = xj[k];
            dot += a.x * b.x + a.y * b.y + a.z * b.z + a.w * b.w;
        }
        if (kh) part[j] = dot;
        __syncthreads();
        if (!kh) S[(size_t)n * NN + j] = fmaf(dot + part[j], HSCALE, HSCALE);
    }

    // ---- idcg[n] via 6-bin histogram (relevance desc == g asc) ----
    float idcg_c = 0.0f;
    if (t < MM) {
        const int col = t + (t >= n ? 1 : 0);
        int gd = gt[col] - gt[n];
        int gi = gd < 0 ? -gd : gd;
        atomicAdd(&hist[gi], 1);
    }
    __syncthreads();
    if (t == 0) {
        int s = 0;
        for (int g = 0; g < 6; ++g) { s += hist[g]; cum[g] = s; }
    }
    __syncthreads();
    if (t < MM) {
        int p = t, g = 0;
        while (p >= cum[g]) ++g;
        float rel = (float)((1 << (10 - g)) - 1);
        idcg_c = rel / __log2f((float)(p + 2));
    }
    #pragma unroll
    for (int off = 32; off > 0; off >>= 1) idcg_c += __shfl_down(idcg_c, off, 64);
    if (lane == 0) red[wave] = idcg_c;
    __syncthreads();
    if (t == 0) {
        float s = 0.0f;
        for (int w = 0; w < 12; ++w) s += red[w];
        idcg[n] = s;
    }
}

__global__ __launch_bounds__(256) void dgc_body(const float* __restrict__ S,
                                                const int* __restrict__ gt,
                                                float* __restrict__ dcg,
                                                const float* __restrict__ idcg,
                                                unsigned* __restrict__ ticket,
                                                float* __restrict__ out) {
    __shared__ float srow[NN];
    __shared__ float part[4][64];
    __shared__ float redf[4];
    __shared__ int   s_last;

    const int grp  = blockIdx.x;   // 0..5
    const int n    = blockIdx.y;   // 0..383
    const int t    = threadIdx.x;
    const int lane = t & 63;
    const int w    = t >> 6;

    if (t < NN / 4) ((float4*)srow)[t] = ((const float4*)(S + (size_t)n * NN))[t];
    if (t == 0) s_last = 0;
    __syncthreads();

    const int  i_off = grp * 64 + lane;
    const bool valid = i_off < MM;
    const int  col   = valid ? i_off + (i_off >= n ? 1 : 0) : 0;
    const float ri   = srow[col];

    float partial = 0.0f;
    const int c0 = w * 96;
    #pragma unroll 8
    for (int c = c0; c < c0 + 96; ++c) {
        partial += __builtin_amdgcn_rcpf(1.0f + exp2f(ri - srow[c]));
    }
    if (n >= c0 && n < c0 + 96) {    // remove diagonal column (wave-uniform)
        partial -= __builtin_amdgcn_rcpf(1.0f + exp2f(ri - srow[n]));
    }
    part[w][lane] = partial;
    __syncthreads();

    if (w == 0) {
        // self term was exactly 0.5: ind = 1 + (sum - 0.5)
        float ind = part[0][lane] + part[1][lane] + part[2][lane] + part[3][lane] + 0.5f;
        float dcg_i = 0.0f;
        if (valid) {
            int gd = gt[col] - gt[n];
            int gi = gd < 0 ? -gd : gd;
            float rel = (float)((1 << (10 - gi)) - 1);
            dcg_i = rel / __log2f(ind + 1.0f);
        }
        #pragma unroll
        for (int off = 32; off > 0; off >>= 1) dcg_i += __shfl_down(dcg_i, off, 64);
        if (lane == 0) {
            atomicAdd(&dcg[n], dcg_i);
            __threadfence();
            unsigned prev = __hip_atomic_fetch_add(ticket, 1u, __ATOMIC_ACQ_REL,
                                                   __HIP_MEMORY_SCOPE_AGENT);
            if (prev == 6 * NN - 1) s_last = 1;
        }
    }
    __syncthreads();

    // ---- last block of the whole grid finalizes ----
    if (s_last) {
        __threadfence();
        float nd = 0.0f;
        for (int idx = t; idx < NN; idx += 256) {
            float d = __hip_atomic_load(&dcg[idx], __ATOMIC_RELAXED,
                                        __HIP_MEMORY_SCOPE_AGENT);
            nd += d / idcg[idx];     // idcg >= 31 always
        }
        #pragma unroll
        for (int off = 32; off > 0; off >>= 1) nd += __shfl_down(nd, off, 64);
        if (lane == 0) redf[w] = nd;
        __syncthreads();
        if (t == 0) out[0] = 1.0f - (redf[0] + redf[1] + redf[2] + redf[3]) / (float)NN;
    }
}

extern "C" void kernel_launch(void* const* d_in, const int* in_sizes, int n_in,
                              void* d_out, int out_size, void* d_ws, size_t ws_size,
                              hipStream_t stream) {
    const float* ranking = (const float*)d_in[0];
    const int*   gt      = (const int*)d_in[1];
    float*       out     = (float*)d_out;

    float*    S      = (float*)d_ws;              // 384*384
    float*    idcg   = S + (size_t)NN * NN;       // 384
    float*    dcg    = idcg + NN;                 // 384
    unsigned* ticket = (unsigned*)(dcg + NN);     // 1
    float*    XN     = (float*)(ticket + 64);     // 384*256 (64 pad for align)

    dgc_norm<<<96, 256, 0, stream>>>(ranking, XN, dcg, ticket);
    dgc_sim<<<NN, 768, 0, stream>>>(XN, gt, S, idcg);
    dgc_body<<<dim3(6, NN), 256, 0, stream>>>(S, gt, dcg, idcg, ticket, out);
}

// Round 4
// 98.483 us; speedup vs baseline: 1.5591x; 1.5591x over previous
//
#include <hip/hip_runtime.h>

// DGCLoss: 1 - mean NDCG. N=384 rows, D=256 feats, M=383 off-diag cols.
//
// Round 4: kill the device-scope ticket (R3's 80us regression: agent-scope
// ACQ_REL atomics + threadfence = per-block L2 writeback/invalidate on
// non-coherent XCD L2s). Block n is now fully self-contained:
//   dgc_init  : out[0] = 1.0 (d_out is poisoned 0xAA).
//   dgc_fused : block n: split-K GEMV -> srow in LDS (norms inline),
//               sigmoid body (i = t%384, c-half = t/384, 192 serial c),
//               idcg histogram, block reduce, relaxed atomicAdd(out, -ndcg/N).
// No workspace, no fences, 2 launches.

#define NN 384
#define DD 256
#define MM 383
// exp(-d*1000) == exp2(s_i - s_j) with s = ((cos+1)*0.5) * 1000*log2(e)
#define HSCALE 721.3475204444817f   // 0.5 * 1000 * log2(e)

__global__ void dgc_init(float* __restrict__ out) {
    if (threadIdx.x == 0) out[0] = 1.0f;
}

__global__ __launch_bounds__(768) void dgc_fused(const float* __restrict__ x,
                                                 const int* __restrict__ gt,
                                                 float* __restrict__ out) {
    __shared__ float xs[DD];        // raw row n
    __shared__ float pdot[NN];      // K-half partial dot
    __shared__ float pss[NN];       // K-half partial |xj|^2
    __shared__ float sstot[NN];     // full |xj|^2 (need [n] cross-thread)
    __shared__ float srow[NN];      // scaled similarity row
    __shared__ float pbody[2][NN];  // c-half sigmoid partials
    __shared__ float redd[12];
    __shared__ float redi[12];
    __shared__ int   hist[6];
    __shared__ int   cum[6];

    const int n    = blockIdx.x;
    const int t    = threadIdx.x;
    const int lane = t & 63;
    const int wave = t >> 6;
    const int kh   = (t >= NN) ? 1 : 0;   // K-half / c-half selector
    const int j    = t - kh * NN;         // 0..383

    if (t < DD / 4) ((float4*)xs)[t] = ((const float4*)(x + (size_t)n * DD))[t];
    if (t < 6) hist[t] = 0;
    __syncthreads();

    // ---- similarity row: thread (j, kh) does half the K dot + half |xj|^2 ----
    float dotF = 0.0f, ssF = 0.0f;
    {
        const float4* xj = (const float4*)(x + (size_t)j * DD) + kh * 32;
        const float4* xa = (const float4*)xs + kh * 32;
        float dot = 0.0f, ss = 0.0f;
        #pragma unroll 8
        for (int k = 0; k < 32; ++k) {
            float4 a = xa[k], b = xj[k];
            dot = fmaf(a.x, b.x, fmaf(a.y, b.y, fmaf(a.z, b.z, fmaf(a.w, b.w, dot))));
            ss  = fmaf(b.x, b.x, fmaf(b.y, b.y, fmaf(b.z, b.z, fmaf(b.w, b.w, ss))));
        }
        if (kh) { pdot[j] = dot; pss[j] = ss; }
        __syncthreads();
        if (!kh) {
            dotF = dot + pdot[j];
            ssF  = ss + pss[j];
            sstot[j] = ssF;
        }
        __syncthreads();
        if (!kh) {
            float cosv = dotF * __builtin_amdgcn_rsqf(fmaxf(sstot[n], 1e-16f))
                              * __builtin_amdgcn_rsqf(fmaxf(ssF, 1e-16f));
            srow[j] = fmaf(cosv, HSCALE, HSCALE);
        }
        __syncthreads();
    }

    // ---- sigmoid body: i = j (0..382 valid), c in [kh*192, kh*192+192) ----
    const bool  valid = (j < MM);
    const int   col   = valid ? (j + (j >= n ? 1 : 0)) : 0;
    const float ri    = srow[col];

    float partial = 0.0f;
    const int c0 = kh * 192;
    #pragma unroll 8
    for (int c = c0; c < c0 + 192; ++c) {
        partial += __builtin_amdgcn_rcpf(1.0f + exp2f(ri - srow[c]));
    }
    if (n >= c0 && n < c0 + 192) {   // remove diagonal column (uniform branch)
        partial -= __builtin_amdgcn_rcpf(1.0f + exp2f(ri - srow[n]));
    }
    pbody[kh][j] = partial;

    int gi = 0;
    if (valid) {
        int gd = gt[col] - gt[n];
        gi = gd < 0 ? -gd : gd;                  // 0..5
        if (!kh) atomicAdd(&hist[gi], 1);
    }
    __syncthreads();
    if (t == 0) {
        int s = 0;
        for (int g = 0; g < 6; ++g) { s += hist[g]; cum[g] = s; }
    }
    __syncthreads();

    // ---- per-i dcg + idcg (kh=0 threads only), then block reduce ----
    float dcg_i = 0.0f, idcg_i = 0.0f;
    if (!kh && valid) {
        // self term (c == col) was exactly 0.5: ind = 1 + (sum - 0.5)
        float ind = pbody[0][j] + pbody[1][j] + 0.5f;
        float rel = (float)((1 << (10 - gi)) - 1);
        dcg_i = rel / __log2f(ind + 1.0f);
        int p = j, g = 0;
        while (p >= cum[g]) ++g;                 // cum[5] == 383 > p always
        idcg_i = (float)((1 << (10 - g)) - 1) / __log2f((float)(p + 2));
    }
    #pragma unroll
    for (int off = 32; off > 0; off >>= 1) {
        dcg_i  += __shfl_down(dcg_i,  off, 64);
        idcg_i += __shfl_down(idcg_i, off, 64);
    }
    if (lane == 0) { redd[wave] = dcg_i; redi[wave] = idcg_i; }
    __syncthreads();
    if (t == 0) {
        float d = 0.0f, id = 0.0f;
        for (int w = 0; w < 12; ++w) { d += redd[w]; id += redi[w]; }
        atomicAdd(out, -(d / id) * (1.0f / (float)NN));   // relaxed, 384 adders
    }
}

extern "C" void kernel_launch(void* const* d_in, const int* in_sizes, int n_in,
                              void* d_out, int out_size, void* d_ws, size_t ws_size,
                              hipStream_t stream) {
    const float* ranking = (const float*)d_in[0];
    const int*   gt      = (const int*)d_in[1];
    float*       out     = (float*)d_out;

    dgc_init<<<1, 64, 0, stream>>>(out);
    dgc_fused<<<NN, 768, 0, stream>>>(ranking, gt, out);
}

// Round 5
// 87.674 us; speedup vs baseline: 1.7513x; 1.1233x over previous
//
#include <hip/hip_runtime.h>

// DGCLoss: 1 - mean NDCG. N=384 rows, D=256 feats, M=383 off-diag cols.
//
// Round 5: coalescing fix. R4's 47us was the gram GEMV reading row j per
// thread j (stride-1024B -> 64 cache lines per load instr, L1-serialized).
// Now: dgc_normT builds XT[k][j] = normalized X^T once (LDS-tiled),
// dgc_fused's gram phase reads XT coalesced (lane-consecutive j, float4),
// xs[k] broadcast from LDS. Body phase unchanged from R4 (proven).
//   dgc_normT : 24 blocks: 16-row tile -> norms -> write XT; b0 sets out=1.
//   dgc_fused : block n: coalesced gram -> srow in LDS -> sigmoid body ->
//               idcg histogram -> relaxed atomicAdd(out, -ndcg/N).

#define NN 384
#define DD 256
#define MM 383
// exp(-d*1000) == exp2(s_i - s_j) with s = ((cos+1)*0.5) * 1000*log2(e)
#define HSCALE 721.3475204444817f   // 0.5 * 1000 * log2(e)

__global__ __launch_bounds__(256) void dgc_normT(const float* __restrict__ x,
                                                 float* __restrict__ XT,
                                                 float* __restrict__ out) {
    __shared__ float xs[16][260];   // +4 pad: conflict-free row-major access
    __shared__ float invn[16];

    const int t  = threadIdx.x;
    const int r0 = blockIdx.x * 16;

    if (blockIdx.x == 0 && t == 0) out[0] = 1.0f;

    // ---- coalesced load of 16 rows ----
    #pragma unroll
    for (int i = 0; i < 4; ++i) {
        int f = t + i * 256;            // float4 unit 0..1023
        int r = f >> 6, c4 = f & 63;
        float4 v = ((const float4*)(x + (size_t)(r0 + r) * DD))[c4];
        xs[r][c4 * 4 + 0] = v.x; xs[r][c4 * 4 + 1] = v.y;
        xs[r][c4 * 4 + 2] = v.z; xs[r][c4 * 4 + 3] = v.w;
    }
    __syncthreads();

    // ---- row norms: 16 threads per row, shfl_xor reduce within wave ----
    {
        const int r = t >> 4, sub = t & 15;
        float s = 0.0f;
        #pragma unroll
        for (int m = 0; m < 16; ++m) {
            float v = xs[r][sub * 16 + m];
            s = fmaf(v, v, s);
        }
        #pragma unroll
        for (int off = 8; off > 0; off >>= 1) s += __shfl_xor(s, off, 64);
        if (sub == 0) invn[r] = __builtin_amdgcn_rsqf(fmaxf(s, 1e-16f));
    }
    __syncthreads();

    // ---- write normalized transpose: XT[k][r0+r] ----
    {
        const int r  = t & 15;
        const int kk = t >> 4;          // 0..15
        const float inv = invn[r];
        #pragma unroll
        for (int i = 0; i < 16; ++i) {
            int k = i * 16 + kk;
            XT[(size_t)k * NN + r0 + r] = xs[r][k] * inv;
        }
    }
}

__global__ __launch_bounds__(768) void dgc_fused(const float* __restrict__ XT,
                                                 const int* __restrict__ gt,
                                                 float* __restrict__ out) {
    __shared__ float  xs[DD];        // normalized row n (column n of XT)
    __shared__ float4 pacc[8][96];   // k-group partial dots (as float4 over j)
    __shared__ float  srow[NN];      // scaled similarity row
    __shared__ float  pbody[2][NN];  // c-half sigmoid partials
    __shared__ float  redd[12], redi[12];
    __shared__ int    hist[6], cum[6];

    const int n    = blockIdx.x;
    const int t    = threadIdx.x;
    const int lane = t & 63;
    const int wave = t >> 6;

    if (t < DD) xs[t] = XT[(size_t)t * NN + n];   // one-time scatter, cheap
    if (t < 6) hist[t] = 0;
    __syncthreads();

    // ---- gram phase: coalesced. j4 = t%96 (4 j's), ks = t/96 (32 k's) ----
    {
        const int j4 = t % 96;
        const int ks = t / 96;
        const float4* XT4 = (const float4*)XT;
        float4 a = {0.0f, 0.0f, 0.0f, 0.0f};
        const int k0 = ks * 32;
        #pragma unroll 8
        for (int m = 0; m < 32; ++m) {
            const int k = k0 + m;
            float4 b = XT4[(size_t)k * 96 + j4];  // lane-consecutive -> 1KB/instr
            float  s = xs[k];                     // LDS broadcast
            a.x = fmaf(s, b.x, a.x); a.y = fmaf(s, b.y, a.y);
            a.z = fmaf(s, b.z, a.z); a.w = fmaf(s, b.w, a.w);
        }
        pacc[ks][j4] = a;
    }
    __syncthreads();
    if (t < NN) {
        const float* pf = (const float*)pacc;     // [8][384] floats
        float s = 0.0f;
        #pragma unroll
        for (int ks = 0; ks < 8; ++ks) s += pf[ks * NN + t];
        srow[t] = fmaf(s, HSCALE, HSCALE);
    }
    __syncthreads();

    // ---- sigmoid body: i = j (0..382 valid), c in [kh*192, +192) ----
    const int   kh    = (t >= NN) ? 1 : 0;
    const int   j     = t - kh * NN;
    const bool  valid = (j < MM);
    const int   col   = valid ? (j + (j >= n ? 1 : 0)) : 0;
    const float ri    = srow[col];

    float partial = 0.0f;
    const int c0 = kh * 192;
    #pragma unroll 8
    for (int c = c0; c < c0 + 192; ++c) {
        partial += __builtin_amdgcn_rcpf(1.0f + exp2f(ri - srow[c]));
    }
    if (n >= c0 && n < c0 + 192) {   // remove diagonal column (uniform branch)
        partial -= __builtin_amdgcn_rcpf(1.0f + exp2f(ri - srow[n]));
    }
    pbody[kh][j] = partial;

    int gi = 0;
    if (valid) {
        int gd = gt[col] - gt[n];
        gi = gd < 0 ? -gd : gd;                  // 0..5
        if (!kh) atomicAdd(&hist[gi], 1);
    }
    __syncthreads();
    if (t == 0) {
        int s = 0;
        for (int g = 0; g < 6; ++g) { s += hist[g]; cum[g] = s; }
    }
    __syncthreads();

    // ---- per-i dcg + idcg (kh=0 threads), block reduce ----
    float dcg_i = 0.0f, idcg_i = 0.0f;
    if (!kh && valid) {
        // self term (c == col) was exactly 0.5: ind = 1 + (sum - 0.5)
        float ind = pbody[0][j] + pbody[1][j] + 0.5f;
        float rel = (float)((1 << (10 - gi)) - 1);
        dcg_i = rel / __log2f(ind + 1.0f);
        int p = j, g = 0;
        while (p >= cum[g]) ++g;                 // cum[5] == 383 > p always
        idcg_i = (float)((1 << (10 - g)) - 1) / __log2f((float)(p + 2));
    }
    #pragma unroll
    for (int off = 32; off > 0; off >>= 1) {
        dcg_i  += __shfl_down(dcg_i,  off, 64);
        idcg_i += __shfl_down(idcg_i, off, 64);
    }
    if (lane == 0) { redd[wave] = dcg_i; redi[wave] = idcg_i; }
    __syncthreads();
    if (t == 0) {
        float d = 0.0f, id = 0.0f;
        for (int w = 0; w < 12; ++w) { d += redd[w]; id += redi[w]; }
        atomicAdd(out, -(d / id) * (1.0f / (float)NN));   // relaxed scope
    }
}

extern "C" void kernel_launch(void* const* d_in, const int* in_sizes, int n_in,
                              void* d_out, int out_size, void* d_ws, size_t ws_size,
                              hipStream_t stream) {
    const float* ranking = (const float*)d_in[0];
    const int*   gt      = (const int*)d_in[1];
    float*       out     = (float*)d_out;
    float*       XT      = (float*)d_ws;     // 256*384 floats = 393 KB

    dgc_normT<<<24, 256, 0, stream>>>(ranking, XT, out);
    dgc_fused<<<NN, 768, 0, stream>>>(XT, gt, out);
}

// Round 6
// 87.627 us; speedup vs baseline: 1.7523x; 1.0005x over previous
//
#include <hip/hip_runtime.h>

// DGCLoss: 1 - mean NDCG. N=384 rows, D=256 feats, M=383 off-diag cols.
//
// Round 6: (a) raw v_exp_f32 via __builtin_amdgcn_exp2f -- libm exp2f
// without fast-math is a checked OCML call (~2x VALU per sigmoid term);
// (b) body grid 768 blocks = exactly 3/CU (R5's 384 = 1.5/CU -> 33% tail);
// (c) separate gram kernel stores S so body reads 1.5KB/block, not 393KB.
//   dgc_normT : 24 blocks: norms -> XT (transposed) + XN (row-major); out=1.
//   dgc_gram  : 96 blocks x 4 rows: S = scaled gram, 4 fma per coalesced load.
//   dgc_body  : block (n, ih): 192 i's x 2 c-halves, raw-exp sigmoid sums,
//               full-row idcg, relaxed atomicAdd(out, -(dcg_half/idcg)/N).

#define NN 384
#define DD 256
#define MM 383
// exp(-d*1000) == exp2(s_i - s_j) with s = ((cos+1)*0.5) * 1000*log2(e)
#define HSCALE 721.3475204444817f   // 0.5 * 1000 * log2(e)

__global__ __launch_bounds__(256) void dgc_normT(const float* __restrict__ x,
                                                 float* __restrict__ XT,
                                                 float* __restrict__ XN,
                                                 float* __restrict__ out) {
    __shared__ float xs[16][260];   // +4 pad: conflict-free
    __shared__ float invn[16];

    const int t  = threadIdx.x;
    const int r0 = blockIdx.x * 16;

    if (blockIdx.x == 0 && t == 0) out[0] = 1.0f;

    #pragma unroll
    for (int i = 0; i < 4; ++i) {
        int f = t + i * 256;            // float4 unit 0..1023
        int r = f >> 6, c4 = f & 63;
        float4 v = ((const float4*)(x + (size_t)(r0 + r) * DD))[c4];
        xs[r][c4 * 4 + 0] = v.x; xs[r][c4 * 4 + 1] = v.y;
        xs[r][c4 * 4 + 2] = v.z; xs[r][c4 * 4 + 3] = v.w;
    }
    __syncthreads();

    {   // row norms: 16 threads per row
        const int r = t >> 4, sub = t & 15;
        float s = 0.0f;
        #pragma unroll
        for (int m = 0; m < 16; ++m) {
            float v = xs[r][sub * 16 + m];
            s = fmaf(v, v, s);
        }
        #pragma unroll
        for (int off = 8; off > 0; off >>= 1) s += __shfl_xor(s, off, 64);
        if (sub == 0) invn[r] = __builtin_amdgcn_rsqf(fmaxf(s, 1e-16f));
    }
    __syncthreads();

    {   // normalized transpose XT[k][r0+r]
        const int r  = t & 15;
        const int kk = t >> 4;
        const float inv = invn[r];
        #pragma unroll
        for (int i = 0; i < 16; ++i) {
            int k = i * 16 + kk;
            XT[(size_t)k * NN + r0 + r] = xs[r][k] * inv;
        }
    }
    {   // normalized row-major XN (coalesced)
        #pragma unroll
        for (int i = 0; i < 4; ++i) {
            int f = t + i * 256;
            int r = f >> 6, c4 = f & 63;
            const float inv = invn[r];
            float4 v;
            v.x = xs[r][c4 * 4 + 0] * inv; v.y = xs[r][c4 * 4 + 1] * inv;
            v.z = xs[r][c4 * 4 + 2] * inv; v.w = xs[r][c4 * 4 + 3] * inv;
            ((float4*)(XN + (size_t)(r0 + r) * DD))[c4] = v;
        }
    }
}

__global__ __launch_bounds__(384) void dgc_gram(const float* __restrict__ XN,
                                                const float* __restrict__ XT,
                                                float* __restrict__ S) {
    __shared__ __align__(16) float xs4[DD][4];   // [k][r], b128 broadcast reads

    const int t  = threadIdx.x;
    const int n0 = blockIdx.x * 4;

    if (t < 256) {
        int r = t >> 6, c4 = t & 63;
        float4 v = ((const float4*)(XN + (size_t)(n0 + r) * DD))[c4];
        xs4[c4 * 4 + 0][r] = v.x; xs4[c4 * 4 + 1][r] = v.y;
        xs4[c4 * 4 + 2][r] = v.z; xs4[c4 * 4 + 3][r] = v.w;
    }
    __syncthreads();

    const int j = t;                               // 0..383, lane-consecutive
    float a0 = 0.f, a1 = 0.f, a2 = 0.f, a3 = 0.f;
    #pragma unroll 8
    for (int k = 0; k < DD; ++k) {
        float b = XT[(size_t)k * NN + j];          // coalesced 256B/wave
        float4 s = *(const float4*)xs4[k];         // ds_read_b128 broadcast
        a0 = fmaf(s.x, b, a0); a1 = fmaf(s.y, b, a1);
        a2 = fmaf(s.z, b, a2); a3 = fmaf(s.w, b, a3);
    }
    S[(size_t)(n0 + 0) * NN + j] = fmaf(a0, HSCALE, HSCALE);
    S[(size_t)(n0 + 1) * NN + j] = fmaf(a1, HSCALE, HSCALE);
    S[(size_t)(n0 + 2) * NN + j] = fmaf(a2, HSCALE, HSCALE);
    S[(size_t)(n0 + 3) * NN + j] = fmaf(a3, HSCALE, HSCALE);
}

__global__ __launch_bounds__(384) void dgc_body(const float* __restrict__ S,
                                                const int* __restrict__ gt,
                                                float* __restrict__ out) {
    __shared__ float srow[NN];
    __shared__ float pbody[2][192];
    __shared__ float redd[3], redi[6];
    __shared__ int   hist[6], cum[6];

    const int n    = blockIdx.x >> 1;
    const int ih   = blockIdx.x & 1;
    const int t    = threadIdx.x;
    const int lane = t & 63;
    const int wave = t >> 6;

    if (t < 96) ((float4*)srow)[t] = ((const float4*)(S + (size_t)n * NN))[t];
    if (t < 6) hist[t] = 0;
    __syncthreads();

    // ---- sigmoid sums: i = ih*192 + t%192, c-half = t/192 (waves 0-2 / 3-5) ----
    const int   il    = t % 192;
    const int   ch    = t / 192;
    const int   i     = ih * 192 + il;
    const bool  valid = (i < MM);
    const int   col   = valid ? (i + (i >= n ? 1 : 0)) : 0;
    const float ri    = srow[col];

    float partial = 0.0f;
    const int c0 = ch * 192;
    #pragma unroll 8
    for (int c = c0; c < c0 + 192; ++c) {
        // raw v_exp_f32 / v_rcp_f32: saturation (inf->0, 0->1) matches the
        // reference's fp32-saturated +-50 clip exactly.
        partial += __builtin_amdgcn_rcpf(1.0f + __builtin_amdgcn_exp2f(ri - srow[c]));
    }
    if (n >= c0 && n < c0 + 192) {   // remove diagonal column (uniform branch)
        partial -= __builtin_amdgcn_rcpf(1.0f + __builtin_amdgcn_exp2f(ri - srow[n]));
    }
    pbody[ch][il] = partial;

    // ---- full-row histogram for idcg (same in both half-blocks) ----
    if (t < MM) {
        int gd = gt[t + (t >= n ? 1 : 0)] - gt[n];
        atomicAdd(&hist[gd < 0 ? -gd : gd], 1);
    }
    __syncthreads();
    if (t == 0) {
        int s = 0;
        for (int g = 0; g < 6; ++g) { s += hist[g]; cum[g] = s; }
    }
    __syncthreads();

    // ---- idcg over all 383 sorted positions ----
    float idcg_i = 0.0f;
    if (t < MM) {
        int p = t, g = 0;
        while (p >= cum[g]) ++g;                 // cum[5]==383 > p always
        idcg_i = (float)((1 << (10 - g)) - 1) / __log2f((float)(p + 2));
    }

    // ---- dcg for this block's 192 i's (ch==0 threads finalize) ----
    float dcg_i = 0.0f;
    if (ch == 0 && valid) {
        // self term (c==col) was exactly 0.5: ind = 1 + (sum - 0.5)
        float ind = pbody[0][il] + pbody[1][il] + 0.5f;
        int gd = gt[col] - gt[n];
        int gi = gd < 0 ? -gd : gd;
        dcg_i = (float)((1 << (10 - gi)) - 1) / __log2f(ind + 1.0f);
    }

    #pragma unroll
    for (int off = 32; off > 0; off >>= 1) {
        dcg_i  += __shfl_down(dcg_i,  off, 64);
        idcg_i += __shfl_down(idcg_i, off, 64);
    }
    if (lane == 0) {
        redi[wave] = idcg_i;
        if (wave < 3) redd[wave] = dcg_i;
    }
    __syncthreads();
    if (t == 0) {
        float d  = redd[0] + redd[1] + redd[2];
        float id = redi[0] + redi[1] + redi[2] + redi[3] + redi[4] + redi[5];
        atomicAdd(out, -(d / id) * (1.0f / (float)NN));   // relaxed scope
    }
}

extern "C" void kernel_launch(void* const* d_in, const int* in_sizes, int n_in,
                              void* d_out, int out_size, void* d_ws, size_t ws_size,
                              hipStream_t stream) {
    const float* ranking = (const float*)d_in[0];
    const int*   gt      = (const int*)d_in[1];
    float*       out     = (float*)d_out;

    float* XT = (float*)d_ws;                  // 256*384
    float* XN = XT + (size_t)DD * NN;          // 384*256
    float* S  = XN + (size_t)NN * DD;          // 384*384

    dgc_normT<<<24, 256, 0, stream>>>(ranking, XT, XN, out);
    dgc_gram<<<96, 384, 0, stream>>>(XN, XT, S);
    dgc_body<<<768, 384, 0, stream>>>(S, gt, out);
}